// Round 4
// baseline (327051.001 us; speedup 1.0000x reference)
//
#include <hip/hip_runtime.h>
#include <math.h>

#define NBLK    32          // worker blocks, all on ONE XCD (its 32 CUs)
#define NLAUNCH 256         // launched blocks; non-elected exit immediately
#define BS      512
#define NSTATE  17
#define NH      256
#define NX      273         // NH + NSTATE
#define WID     1024
#define NT      64
#define NSUB    8
#define ROWS_H  (WID/NBLK)  // 32 rows/block for 1024-wide layers
#define ROWS_L  (NH/NBLK)   // 8 rows/block for the 256-wide output layer
#define POLL_CAP 2000000    // ~0.2s; then declare dead (fail fast, no hang)

typedef unsigned long long u64;

__device__ __forceinline__ float softplus_f(float v) {
    return fmaxf(v, 0.f) + log1pf(expf(-fabsf(v)));
}

// ---- same-XCD L2 exchange, TEAR-PROOF ------------------------------------
// All workers sit on one XCD, so its L2 is a valid coherence point.
// Store: sc0 => write-through L1, lands in the shared L2 (not MALL).
// Load:  sc0 => bypass L1, read the shared L2 (~250 cy vs ~900 cy MALL).
// dwordx2 ops are NOT guaranteed 8B-atomic (R3 failed from torn reads:
// {new tag, old value} passes a plain equality check). Fix: entangle tag
// and value -- word = {tag ^ value : 32 | value : 32}. Accept iff
// hi ^ lo == tag. Any torn combination with v_new != v_old fails and
// re-polls; v_new == v_old tears are harmless by definition.
__device__ __forceinline__ void st_l2(u64* p, float v, unsigned tag) {
    unsigned lo = __float_as_uint(v);
    u64 w = ((u64)(tag ^ lo) << 32) | (u64)lo;
    asm volatile("global_store_dwordx2 %0, %1, off sc0" :: "v"(p), "v"(w) : "memory");
}
__device__ __forceinline__ u64 ld_l2(const u64* p) {
    u64 w;
    asm volatile("global_load_dwordx2 %0, %1, off sc0\n\t"
                 "s_waitcnt vmcnt(0)"
                 : "=v"(w) : "v"(p) : "memory");
    return w;
}
__device__ __forceinline__ void ld_l2_pair(const u64* p0, const u64* p1,
                                           u64& w0, u64& w1) {
    asm volatile("global_load_dwordx2 %0, %2, off sc0\n\t"
                 "global_load_dwordx2 %1, %3, off sc0\n\t"
                 "s_waitcnt vmcnt(0)"
                 : "=&v"(w0), "=&v"(w1) : "v"(p0), "v"(p1) : "memory");
}
__device__ __forceinline__ bool tag_ok(u64 w, unsigned tag) {
    return ((unsigned)(w >> 32) ^ (unsigned)w) == tag;
}

// Poll a 1024-word tagged buffer into LDS. Thread t owns {t, t+512}.
__device__ __forceinline__ void poll_z(const u64* __restrict__ buf, unsigned tag,
                                       float* __restrict__ z_s, int t,
                                       volatile int* dead) {
    const u64* p0 = buf + t;
    const u64* p1 = buf + t + 512;
    u64 w0 = 0, w1 = 0;
    int it = 0;
    for (;;) {
        ld_l2_pair(p0, p1, w0, w1);
        if (tag_ok(w0, tag) & tag_ok(w1, tag)) break;
        if (++it > POLL_CAP) *dead = 1;
        if (*dead) break;
    }
    z_s[t]       = __uint_as_float((unsigned)w0);
    z_s[t + 512] = __uint_as_float((unsigned)w1);
    __syncthreads();
}

extern "C" __global__ __launch_bounds__(BS, 2) void ode_kernel(
    const float* __restrict__ ts,   const float* __restrict__ W0,
    const float* __restrict__ b0,   const float* __restrict__ Wh,
    const float* __restrict__ bh,   const float* __restrict__ Wl,
    const float* __restrict__ bl,   const float* __restrict__ betaW,
    const float* __restrict__ betab,const float* __restrict__ hvec,
    const float* __restrict__ scale,const float* __restrict__ y0log,
    float* __restrict__ out, u64* zA, u64* zB, u64* dhb, unsigned* ctrl)
{
    const int t = threadIdx.x;

    __shared__ int      role_sh;
    __shared__ unsigned tagbase_sh;
    __shared__ int      dead_sh;
    __shared__ float y_s[NX];
    __shared__ float yn_s[NX];
    __shared__ float xm[NX];     // MLP-ordered input: [h(256), state(17)]
    __shared__ float k_s[NX];
    __shared__ float z_s[WID];
    __shared__ float red[8];
    __shared__ float dt_sh;
    extern __shared__ float wh2[];   // dynamic: 32 rows x 1024 of layer-3 (128 KB)

    // ---- XCD election: first XCD to register NBLK blocks wins.
    // 256 blocks x 512 thr, LDS ~140KB -> exactly 1 block/CU, all co-resident.
    // Winner word packs {realtime-nonce:28 | xcd+1:4}; doubles as the
    // per-launch tag base (stale tags from a previous launch never match).
    if (t == 0) {
        int xcd;
        asm volatile("s_getreg_b32 %0, hwreg(HW_REG_XCC_ID)" : "=s"(xcd));
        xcd &= 7;
        unsigned rk = atomicAdd(&ctrl[xcd], 1u);
        if (rk == NBLK - 1) {
            u64 rt;
            asm volatile("s_memrealtime %0\n\ts_waitcnt lgkmcnt(0)" : "=s"(rt));
            unsigned word = (((unsigned)(rt >> 4)) << 4) | (unsigned)(xcd + 1);
            atomicCAS(&ctrl[8], 0u, word);
        }
        unsigned w; int it = 0;
        do {
            w = __hip_atomic_load(&ctrl[8], __ATOMIC_RELAXED, __HIP_MEMORY_SCOPE_AGENT);
        } while (w == 0u && ++it < POLL_CAP);
        int winner = (int)(w & 0xFu) - 1;
        role_sh    = (w != 0u && xcd == winner && rk < NBLK) ? (int)rk : -1;
        tagbase_sh = w;
        dead_sh    = 0;
    }
    __syncthreads();
    const int blk = role_sh;
    const unsigned tagbase = tagbase_sh;
    if (blk < 0) return;

    const float scale0 = scale[0];
    const float betab0 = betab[0];
    unsigned R = 0;   // exchange round; tag = tagbase + R

    const int rowH = t >> 4, laneH = t & 15;
    const int growH = blk * ROWS_H + rowH;
    const int rowL = t >> 6, laneL = t & 63;
    const int growL = blk * ROWS_L + rowL;

    // ---- loop-invariant scalars ----
    const float b0r = b0[growH];
    float bhr[3];
    bhr[0] = bh[growH]; bhr[1] = bh[WID + growH]; bhr[2] = bh[2 * WID + growH];
    const float blr    = bl[growL];
    const float betaWr = (t < NH) ? betaW[t] : 0.f;
    const float* wlp = Wl + (size_t)growL * WID + laneL * 4;

    // ---- weight residency: h1,h2 in VGPRs (128), h3 slice in LDS (128KB),
    //      W0 in 18 regs, Wl streamed per stage (L2-resident).
    float4 wv0[16], wv1[16];
    {
        const float* whp = Wh + (size_t)growH * WID + laneH * 4;
        #pragma unroll
        for (int i = 0; i < 16; i++) wv0[i] = *(const float4*)(whp + i * 64);
        #pragma unroll
        for (int i = 0; i < 16; i++) wv1[i] = *(const float4*)(whp + WID * WID + i * 64);
    }
    {   // copy layer-3 row slice into LDS (coalesced float4)
        const float* src = Wh + 2 * (size_t)WID * WID + (size_t)blk * ROWS_H * WID;
        for (int i = t * 4; i < ROWS_H * WID; i += BS * 4)
            *(float4*)&wh2[i] = *(const float4*)&src[i];
    }
    float w0r[18];
    {
        const float* w0p = W0 + (size_t)growH * NX;
        #pragma unroll
        for (int i = 0; i < 18; i++) {
            int c = laneH + i * 16;
            w0r[i] = (c < NX) ? w0p[c] : 0.f;
        }
    }

    // ---- y0 = [softmax(y0_log), hvec] ----
    if (t < NSTATE) {
        float m = -1e30f;
        for (int j = 0; j < NSTATE; j++) m = fmaxf(m, y0log[j]);
        float ssum = 0.f;
        for (int j = 0; j < NSTATE; j++) ssum += expf(y0log[j] - m);
        y_s[t] = expf(y0log[t] - m) / ssum;
    }
    if (t < NH) y_s[NSTATE + t] = hvec[t];
    __syncthreads();

    if (blk == 0) {
        if (t < NSTATE) out[t] = y_s[t];
        if (t < NH)     out[NT * NSTATE + t] = y_s[NSTATE + t];
    }

    const float c_xi = 13.f / 12.f, c_mu = 0.041f / 12.f, c_sig = 91.f / 12.f,
                c_nu = 36.f / 12.f, c_gam = 1.8f / 12.f;

    for (int iv = 0; iv < NT - 1; iv++) {
        if (t == 0) dt_sh = (ts[iv + 1] - ts[iv]) * (1.f / NSUB);
        __syncthreads();
        const float dt = dt_sh;

        for (int sub = 0; sub < NSUB; sub++) {
            if (t < NX) yn_s[t] = y_s[t];

            for (int s = 0; s < 4; s++) {
                const float a   = (s == 0) ? 0.f : ((s == 3) ? 1.f : 0.5f);
                const float wgt = ((s == 0) || (s == 3)) ? dt * (1.f / 6.f) : dt * (1.f / 3.f);

                // ---- stage input, built directly in MLP order [h, state] ----
                if (t < NX) {
                    const int src = (t < NH) ? (NSTATE + t) : (t - NH);
                    float v = y_s[src];
                    if (s != 0) v += a * dt * k_s[src];
                    xm[t] = v;
                }
                __syncthreads();

                // ---- L0: 1024x273, weights in regs ----
                {
                    float acc = 0.f;
                    #pragma unroll
                    for (int i = 0; i < 18; i++) {
                        int c = laneH + i * 16;
                        if (c < NX) acc += w0r[i] * xm[c];
                    }
                    #pragma unroll
                    for (int m = 1; m < 16; m <<= 1) acc += __shfl_xor(acc, m, 16);
                    ++R;
                    if (laneH == 0) st_l2(&zA[growH], softplus_f(acc + b0r), tagbase + R);
                }

                // ---- beta head + dstate: off the critical path ----
                {
                    if (t < NH) {
                        float p = betaWr * xm[t];
                        #pragma unroll
                        for (int m = 1; m < 64; m <<= 1) p += __shfl_xor(p, m, 64);
                        if ((t & 63) == 0) red[t >> 6] = p;
                    }
                    __syncthreads();
                    if (t == 0) {
                        const float* xs = xm + NH;
                        float sd  = red[0] + red[1] + red[2] + red[3] + betab0;
                        float bb1 = 8.f / (1.f + expf(-sd)) + 25.f;
                        float bb2 = 0.5f * bb1, bb3 = 0.35f * bb1, bb4 = 0.25f * bb1;
                        float M  = xs[0],  S1 = xs[1],  E1 = xs[2],  E2 = xs[3];
                        float E3 = xs[4],  E4 = xs[5],  I1 = xs[6],  I2 = xs[7];
                        float I3 = xs[8],  I4 = xs[9],  R1 = xs[10], R2 = xs[11];
                        float R3 = xs[12], R4 = xs[13], S2 = xs[14], S3 = xs[15];
                        float S4 = xs[16];
                        float I = I1 + I2 + I3 + I4, Rs = R1 + R2 + R3 + R4;
                        k_s[0]  = Rs * c_mu - (c_xi + c_mu) * M;
                        k_s[1]  = c_mu * (1.f - Rs) + c_xi * M - c_mu * S1 - bb1 * I * S1;
                        k_s[2]  = bb1 * I * S1 - (c_mu + c_sig) * E1;
                        k_s[3]  = bb2 * I * S2 - (c_mu + c_sig) * E2;
                        k_s[4]  = bb3 * I * S3 - (c_mu + c_sig) * E3;
                        k_s[5]  = bb4 * I * S4 - (c_mu + c_sig) * E4;
                        k_s[6]  = c_sig * E1 - (c_nu + c_mu) * I1;
                        k_s[7]  = c_sig * E2 - (c_nu + c_mu) * I2;
                        k_s[8]  = c_sig * E3 - (c_nu + c_mu) * I3;
                        k_s[9]  = c_sig * E4 - (c_nu + c_mu) * I4;
                        k_s[10] = c_nu * I1 - (c_mu + c_gam) * R1;
                        k_s[11] = c_nu * I2 - (c_mu + c_gam) * R2;
                        k_s[12] = c_nu * I3 - (c_mu + c_gam) * R3;
                        k_s[13] = c_nu * I4 - (c_mu + c_gam) * R4;
                        k_s[14] = c_gam * R1 - c_mu * S2 - bb2 * I * S2;
                        k_s[15] = c_gam * R2 - c_mu * S3 - bb3 * I * S3;
                        k_s[16] = c_gam * (R3 + R4) - c_mu * S4 - bb4 * I * S4;
                    }
                    // k_s[0..16] is next read only after later poll barriers.
                }

                // ---- h1, h2: weights in registers ----
                auto hidden = [&](const float4 (&wv)[16], const u64* zin,
                                  u64* zout, float bias) {
                    poll_z(zin, tagbase + R, z_s, t, &dead_sh);
                    float acc = 0.f;
                    #pragma unroll
                    for (int i = 0; i < 16; i++) {
                        float4 zv = *(const float4*)(z_s + (laneH * 4 + i * 64));
                        acc += wv[i].x * zv.x + wv[i].y * zv.y +
                               wv[i].z * zv.z + wv[i].w * zv.w;
                    }
                    #pragma unroll
                    for (int m = 1; m < 16; m <<= 1) acc += __shfl_xor(acc, m, 16);
                    ++R;
                    if (laneH == 0) st_l2(&zout[growH], softplus_f(acc + bias), tagbase + R);
                };

                hidden(wv0, zA, zB, bhr[0]);
                hidden(wv1, zB, zA, bhr[1]);

                // prefetch Wl row slice (L2-resident); overlaps h3 exchange
                float4 wvL[4];
                #pragma unroll
                for (int i = 0; i < 4; i++) wvL[i] = *(const float4*)(wlp + i * 256);

                // ---- h3: weights from LDS ----
                {
                    poll_z(zA, tagbase + R, z_s, t, &dead_sh);
                    const float* wr = wh2 + rowH * WID + laneH * 4;
                    float acc = 0.f;
                    #pragma unroll
                    for (int i = 0; i < 16; i++) {
                        float4 wv4 = *(const float4*)(wr + i * 64);
                        float4 zv  = *(const float4*)(z_s + (laneH * 4 + i * 64));
                        acc += wv4.x * zv.x + wv4.y * zv.y +
                               wv4.z * zv.z + wv4.w * zv.w;
                    }
                    #pragma unroll
                    for (int m = 1; m < 16; m <<= 1) acc += __shfl_xor(acc, m, 16);
                    ++R;
                    if (laneH == 0) st_l2(&zB[growH], softplus_f(acc + bhr[2]), tagbase + R);
                }

                // ---- Wl: 256x1024, 8 rows/block; tanh epilogue ----
                {
                    poll_z(zB, tagbase + R, z_s, t, &dead_sh);
                    float acc = 0.f;
                    #pragma unroll
                    for (int i = 0; i < 4; i++) {
                        float4 zv = *(const float4*)(z_s + (laneL * 4 + i * 256));
                        acc += wvL[i].x * zv.x + wvL[i].y * zv.y +
                               wvL[i].z * zv.z + wvL[i].w * zv.w;
                    }
                    #pragma unroll
                    for (int m = 1; m < 64; m <<= 1) acc += __shfl_xor(acc, m, 64);
                    ++R;
                    if (laneL == 0)
                        st_l2(&dhb[growL], scale0 * tanhf(0.01f * (acc + blr)), tagbase + R);
                }

                // ---- gather dh (one word per thread t<256) ----
                {
                    if (t < NH) {
                        u64 w; int it = 0;
                        volatile int* dead = &dead_sh;
                        for (;;) {
                            w = ld_l2(dhb + t);
                            if (tag_ok(w, tagbase + R)) break;
                            if (++it > POLL_CAP) *dead = 1;
                            if (*dead) break;
                        }
                        k_s[NSTATE + t] = __uint_as_float((unsigned)w);
                    }
                    __syncthreads();
                    if (t < NX) yn_s[t] += wgt * k_s[t];
                }
            } // stages

            __syncthreads();
            if (t < NX) y_s[t] = yn_s[t];
            __syncthreads();
        } // substeps

        if (blk == 0) {
            if (t < NSTATE) out[(iv + 1) * NSTATE + t] = y_s[t];
            if (t < NH)     out[NT * NSTATE + (iv + 1) * NH + t] = y_s[NSTATE + t];
        }
    } // intervals
}

extern "C" void kernel_launch(void* const* d_in, const int* in_sizes, int n_in,
                              void* d_out, int out_size, void* d_ws, size_t ws_size,
                              hipStream_t stream) {
    const float* ts    = (const float*)d_in[0];
    const float* W0    = (const float*)d_in[1];
    const float* b0    = (const float*)d_in[2];
    const float* Wh    = (const float*)d_in[3];
    const float* bh    = (const float*)d_in[4];
    const float* Wl    = (const float*)d_in[5];
    const float* bl    = (const float*)d_in[6];
    const float* betaW = (const float*)d_in[7];
    const float* betab = (const float*)d_in[8];
    const float* hvec  = (const float*)d_in[9];
    const float* scale = (const float*)d_in[10];
    const float* y0log = (const float*)d_in[11];
    float* out = (float*)d_out;

    u64*      zA   = (u64*)d_ws;                          // 8 KB
    u64*      zB   = (u64*)((char*)d_ws + 8192);          // 8 KB
    u64*      dhb  = (u64*)((char*)d_ws + 16384);         // 2 KB
    unsigned* ctrl = (unsigned*)((char*)d_ws + 18432);    // cnt[8], winner word

    // allow 128KB dynamic LDS (h3 weight slice); host-side attr, capture-safe
    static int lds_set = 0;
    if (!lds_set) {
        hipFuncSetAttribute((const void*)ode_kernel,
                            hipFuncAttributeMaxDynamicSharedMemorySize, 131072);
        lds_set = 1;
    }

    // zero tags + election state (tag 0 != any tagbase+R with nonzero nonce)
    hipMemsetAsync(d_ws, 0, 18432 + 64, stream);
    hipLaunchKernelGGL(ode_kernel, dim3(NLAUNCH), dim3(BS), 131072, stream,
                       ts, W0, b0, Wh, bh, Wl, bl, betaW, betab, hvec, scale,
                       y0log, out, zA, zB, dhb, ctrl);
}

// Round 5
// 25209.598 us; speedup vs baseline: 12.9733x; 12.9733x over previous
//
#include <hip/hip_runtime.h>
#include <math.h>

#define NBLK    32          // worker blocks, all on ONE XCD (its 32 CUs)
#define NLAUNCH 256         // launched blocks; non-elected exit immediately
#define BS      512
#define NSTATE  17
#define NH      256
#define NX      273         // NH + NSTATE
#define WID     1024
#define NT      64
#define NSUB    8
#define ROWS_H  (WID/NBLK)  // 32 rows/block for 1024-wide layers
#define ROWS_L  (NH/NBLK)   // 8 rows/block for the 256-wide output layer
#define POLL_CAP 2000000    // fail fast instead of hanging

typedef unsigned long long u64;

__device__ __forceinline__ float softplus_f(float v) {
    return fmaxf(v, 0.f) + log1pf(expf(-fabsf(v)));
}

// ---- same-XCD L2 exchange via L2 ATOMIC UNITS -----------------------------
// R4 lesson: sc0 loads are SE-scope and can be served by a STALE L1 line
// until eviction (~32us/poll -> 327ms). Atomics never execute in L1: a
// default-scope atomic RMW is serviced at the XCD's L2 (~300cy RTT, and all
// 32 workers share that L2 by election). So:
//   store = global_atomic_swap_x2  (64b single-copy atomic, lands in L2)
//   load  = global_atomic_add_x2 +0, sc0 (returns current L2 value)
// Tag carries a per-launch nonce (stale lines from prior launches never
// match) and is XOR-entangled with the value (tear-proof by construction).
__device__ __forceinline__ void st_l2(u64* p, float v, unsigned tag) {
    unsigned lo = __float_as_uint(v);
    u64 w = ((u64)(tag ^ lo) << 32) | (u64)lo;
    asm volatile("global_atomic_swap_x2 %0, %1, off" :: "v"(p), "v"(w) : "memory");
}
__device__ __forceinline__ u64 ld_l2(const u64* p) {
    u64 w;
    asm volatile("global_atomic_add_x2 %0, %1, %2, off sc0\n\t"
                 "s_waitcnt vmcnt(0)"
                 : "=&v"(w) : "v"(p), "v"(0ULL) : "memory");
    return w;
}
__device__ __forceinline__ void ld_l2_pair(const u64* p0, const u64* p1,
                                           u64& w0, u64& w1) {
    asm volatile("global_atomic_add_x2 %0, %2, %4, off sc0\n\t"
                 "global_atomic_add_x2 %1, %3, %4, off sc0\n\t"
                 "s_waitcnt vmcnt(0)"
                 : "=&v"(w0), "=&v"(w1) : "v"(p0), "v"(p1), "v"(0ULL) : "memory");
}
__device__ __forceinline__ bool tag_ok(u64 w, unsigned tag) {
    return ((unsigned)(w >> 32) ^ (unsigned)w) == tag;
}

// Poll a 1024-word tagged buffer into LDS. Thread t owns {t, t+512}.
__device__ __forceinline__ void poll_z(const u64* __restrict__ buf, unsigned tag,
                                       float* __restrict__ z_s, int t,
                                       volatile int* dead) {
    const u64* p0 = buf + t;
    const u64* p1 = buf + t + 512;
    u64 w0 = 0, w1 = 0;
    int it = 0;
    for (;;) {
        ld_l2_pair(p0, p1, w0, w1);
        if (tag_ok(w0, tag) & tag_ok(w1, tag)) break;
        if (++it > POLL_CAP) *dead = 1;
        if (*dead) break;
    }
    z_s[t]       = __uint_as_float((unsigned)w0);
    z_s[t + 512] = __uint_as_float((unsigned)w1);
    __syncthreads();
}

extern "C" __global__ __launch_bounds__(BS, 2) void ode_kernel(
    const float* __restrict__ ts,   const float* __restrict__ W0,
    const float* __restrict__ b0,   const float* __restrict__ Wh,
    const float* __restrict__ bh,   const float* __restrict__ Wl,
    const float* __restrict__ bl,   const float* __restrict__ betaW,
    const float* __restrict__ betab,const float* __restrict__ hvec,
    const float* __restrict__ scale,const float* __restrict__ y0log,
    float* __restrict__ out, u64* zA, u64* zB, u64* dhb, unsigned* ctrl)
{
    const int t = threadIdx.x;

    __shared__ int      role_sh;
    __shared__ unsigned tagbase_sh;
    __shared__ int      dead_sh;
    __shared__ float y_s[NX];
    __shared__ float yn_s[NX];
    __shared__ float xm[NX];     // MLP-ordered input: [h(256), state(17)]
    __shared__ float k_s[NX];
    __shared__ float z_s[WID];
    __shared__ float red[8];
    __shared__ float dt_sh;
    extern __shared__ float wh2[];   // dynamic: 32 rows x 1024 of layer-3 (128 KB)

    // ---- XCD election: first XCD to register NBLK blocks wins (MALL atomics,
    // one-time cost). 256 blocks, ~137KB LDS -> 1 block/CU, all co-resident.
    // Winner word packs {realtime-nonce:28 | xcd+1:4}; doubles as tag base.
    if (t == 0) {
        int xcd;
        asm volatile("s_getreg_b32 %0, hwreg(HW_REG_XCC_ID)" : "=s"(xcd));
        xcd &= 7;
        unsigned rk = atomicAdd(&ctrl[xcd], 1u);
        if (rk == NBLK - 1) {
            u64 rt;
            asm volatile("s_memrealtime %0\n\ts_waitcnt lgkmcnt(0)" : "=s"(rt));
            unsigned word = (((unsigned)(rt >> 4)) << 4) | (unsigned)(xcd + 1);
            atomicCAS(&ctrl[8], 0u, word);
        }
        unsigned w; int it = 0;
        do {
            w = __hip_atomic_load(&ctrl[8], __ATOMIC_RELAXED, __HIP_MEMORY_SCOPE_AGENT);
        } while (w == 0u && ++it < POLL_CAP);
        int winner = (int)(w & 0xFu) - 1;
        role_sh    = (w != 0u && xcd == winner && rk < NBLK) ? (int)rk : -1;
        tagbase_sh = w;
        dead_sh    = 0;
    }
    __syncthreads();
    const int blk = role_sh;
    const unsigned tagbase = tagbase_sh;
    if (blk < 0) return;

    const float scale0 = scale[0];
    const float betab0 = betab[0];
    unsigned R = 0;   // exchange round; tag = tagbase + R

    const int rowH = t >> 4, laneH = t & 15;
    const int growH = blk * ROWS_H + rowH;
    const int rowL = t >> 6, laneL = t & 63;
    const int growL = blk * ROWS_L + rowL;

    // ---- loop-invariant scalars ----
    const float b0r = b0[growH];
    float bhr[3];
    bhr[0] = bh[growH]; bhr[1] = bh[WID + growH]; bhr[2] = bh[2 * WID + growH];
    const float blr    = bl[growL];
    const float betaWr = (t < NH) ? betaW[t] : 0.f;
    const float* wlp = Wl + (size_t)growL * WID + laneL * 4;

    // ---- weight residency: h1,h2 in VGPRs (128), h3 slice in LDS (128KB),
    //      W0 in 18 regs, Wl streamed per stage (L2-resident).
    float4 wv0[16], wv1[16];
    {
        const float* whp = Wh + (size_t)growH * WID + laneH * 4;
        #pragma unroll
        for (int i = 0; i < 16; i++) wv0[i] = *(const float4*)(whp + i * 64);
        #pragma unroll
        for (int i = 0; i < 16; i++) wv1[i] = *(const float4*)(whp + WID * WID + i * 64);
    }
    {   // copy layer-3 row slice into LDS (coalesced float4)
        const float* src = Wh + 2 * (size_t)WID * WID + (size_t)blk * ROWS_H * WID;
        for (int i = t * 4; i < ROWS_H * WID; i += BS * 4)
            *(float4*)&wh2[i] = *(const float4*)&src[i];
    }
    float w0r[18];
    {
        const float* w0p = W0 + (size_t)growH * NX;
        #pragma unroll
        for (int i = 0; i < 18; i++) {
            int c = laneH + i * 16;
            w0r[i] = (c < NX) ? w0p[c] : 0.f;
        }
    }

    // ---- y0 = [softmax(y0_log), hvec] ----
    if (t < NSTATE) {
        float m = -1e30f;
        for (int j = 0; j < NSTATE; j++) m = fmaxf(m, y0log[j]);
        float ssum = 0.f;
        for (int j = 0; j < NSTATE; j++) ssum += expf(y0log[j] - m);
        y_s[t] = expf(y0log[t] - m) / ssum;
    }
    if (t < NH) y_s[NSTATE + t] = hvec[t];
    __syncthreads();

    if (blk == 0) {
        if (t < NSTATE) out[t] = y_s[t];
        if (t < NH)     out[NT * NSTATE + t] = y_s[NSTATE + t];
    }

    const float c_xi = 13.f / 12.f, c_mu = 0.041f / 12.f, c_sig = 91.f / 12.f,
                c_nu = 36.f / 12.f, c_gam = 1.8f / 12.f;

    for (int iv = 0; iv < NT - 1; iv++) {
        if (t == 0) dt_sh = (ts[iv + 1] - ts[iv]) * (1.f / NSUB);
        __syncthreads();
        const float dt = dt_sh;

        for (int sub = 0; sub < NSUB; sub++) {
            if (t < NX) yn_s[t] = y_s[t];

            for (int s = 0; s < 4; s++) {
                const float a   = (s == 0) ? 0.f : ((s == 3) ? 1.f : 0.5f);
                const float wgt = ((s == 0) || (s == 3)) ? dt * (1.f / 6.f) : dt * (1.f / 3.f);
                const float adt = a * dt;

                // ---- stage input, built directly in MLP order [h, state] ----
                if (t < NX) {
                    const int src = (t < NH) ? (NSTATE + t) : (t - NH);
                    float v = y_s[src];
                    if (s != 0) v = fmaf(adt, k_s[src], v);
                    xm[t] = v;
                }
                __syncthreads();

                // ---- L0: 1024x273, weights in regs (fmaf-pinned) ----
                {
                    float acc = 0.f;
                    #pragma unroll
                    for (int i = 0; i < 18; i++) {
                        int c = laneH + i * 16;
                        if (c < NX) acc = fmaf(w0r[i], xm[c], acc);
                    }
                    #pragma unroll
                    for (int m = 1; m < 16; m <<= 1) acc += __shfl_xor(acc, m, 16);
                    ++R;
                    if (laneH == 0) st_l2(&zA[growH], softplus_f(acc + b0r), tagbase + R);
                }

                // ---- beta head + dstate: off the critical path ----
                {
                    if (t < NH) {
                        float p = betaWr * xm[t];
                        #pragma unroll
                        for (int m = 1; m < 64; m <<= 1) p += __shfl_xor(p, m, 64);
                        if ((t & 63) == 0) red[t >> 6] = p;
                    }
                    __syncthreads();
                    if (t == 0) {
                        const float* xs = xm + NH;
                        float sd  = red[0] + red[1] + red[2] + red[3] + betab0;
                        float bb1 = 8.f / (1.f + expf(-sd)) + 25.f;
                        float bb2 = 0.5f * bb1, bb3 = 0.35f * bb1, bb4 = 0.25f * bb1;
                        float M  = xs[0],  S1 = xs[1],  E1 = xs[2],  E2 = xs[3];
                        float E3 = xs[4],  E4 = xs[5],  I1 = xs[6],  I2 = xs[7];
                        float I3 = xs[8],  I4 = xs[9],  R1 = xs[10], R2 = xs[11];
                        float R3 = xs[12], R4 = xs[13], S2 = xs[14], S3 = xs[15];
                        float S4 = xs[16];
                        float I = I1 + I2 + I3 + I4, Rs = R1 + R2 + R3 + R4;
                        k_s[0]  = Rs * c_mu - (c_xi + c_mu) * M;
                        k_s[1]  = c_mu * (1.f - Rs) + c_xi * M - c_mu * S1 - bb1 * I * S1;
                        k_s[2]  = bb1 * I * S1 - (c_mu + c_sig) * E1;
                        k_s[3]  = bb2 * I * S2 - (c_mu + c_sig) * E2;
                        k_s[4]  = bb3 * I * S3 - (c_mu + c_sig) * E3;
                        k_s[5]  = bb4 * I * S4 - (c_mu + c_sig) * E4;
                        k_s[6]  = c_sig * E1 - (c_nu + c_mu) * I1;
                        k_s[7]  = c_sig * E2 - (c_nu + c_mu) * I2;
                        k_s[8]  = c_sig * E3 - (c_nu + c_mu) * I3;
                        k_s[9]  = c_sig * E4 - (c_nu + c_mu) * I4;
                        k_s[10] = c_nu * I1 - (c_mu + c_gam) * R1;
                        k_s[11] = c_nu * I2 - (c_mu + c_gam) * R2;
                        k_s[12] = c_nu * I3 - (c_mu + c_gam) * R3;
                        k_s[13] = c_nu * I4 - (c_mu + c_gam) * R4;
                        k_s[14] = c_gam * R1 - c_mu * S2 - bb2 * I * S2;
                        k_s[15] = c_gam * R2 - c_mu * S3 - bb3 * I * S3;
                        k_s[16] = c_gam * (R3 + R4) - c_mu * S4 - bb4 * I * S4;
                    }
                    // k_s[0..16] is next read only after later poll barriers.
                }

                // ---- h1, h2: weights in registers (fmaf-pinned) ----
                auto hidden = [&](const float4 (&wv)[16], const u64* zin,
                                  u64* zout, float bias) {
                    poll_z(zin, tagbase + R, z_s, t, &dead_sh);
                    float acc = 0.f;
                    #pragma unroll
                    for (int i = 0; i < 16; i++) {
                        float4 zv = *(const float4*)(z_s + (laneH * 4 + i * 64));
                        acc = fmaf(wv[i].x, zv.x, acc);
                        acc = fmaf(wv[i].y, zv.y, acc);
                        acc = fmaf(wv[i].z, zv.z, acc);
                        acc = fmaf(wv[i].w, zv.w, acc);
                    }
                    #pragma unroll
                    for (int m = 1; m < 16; m <<= 1) acc += __shfl_xor(acc, m, 16);
                    ++R;
                    if (laneH == 0) st_l2(&zout[growH], softplus_f(acc + bias), tagbase + R);
                };

                hidden(wv0, zA, zB, bhr[0]);
                hidden(wv1, zB, zA, bhr[1]);

                // prefetch Wl row slice (L2-resident); overlaps h3 exchange
                float4 wvL[4];
                #pragma unroll
                for (int i = 0; i < 4; i++) wvL[i] = *(const float4*)(wlp + i * 256);

                // ---- h3: weights from LDS (fmaf-pinned) ----
                {
                    poll_z(zA, tagbase + R, z_s, t, &dead_sh);
                    const float* wr = wh2 + rowH * WID + laneH * 4;
                    float acc = 0.f;
                    #pragma unroll
                    for (int i = 0; i < 16; i++) {
                        float4 wv4 = *(const float4*)(wr + i * 64);
                        float4 zv  = *(const float4*)(z_s + (laneH * 4 + i * 64));
                        acc = fmaf(wv4.x, zv.x, acc);
                        acc = fmaf(wv4.y, zv.y, acc);
                        acc = fmaf(wv4.z, zv.z, acc);
                        acc = fmaf(wv4.w, zv.w, acc);
                    }
                    #pragma unroll
                    for (int m = 1; m < 16; m <<= 1) acc += __shfl_xor(acc, m, 16);
                    ++R;
                    if (laneH == 0) st_l2(&zB[growH], softplus_f(acc + bhr[2]), tagbase + R);
                }

                // ---- Wl: 256x1024, 8 rows/block; tanh epilogue ----
                {
                    poll_z(zB, tagbase + R, z_s, t, &dead_sh);
                    float acc = 0.f;
                    #pragma unroll
                    for (int i = 0; i < 4; i++) {
                        float4 zv = *(const float4*)(z_s + (laneL * 4 + i * 256));
                        acc = fmaf(wvL[i].x, zv.x, acc);
                        acc = fmaf(wvL[i].y, zv.y, acc);
                        acc = fmaf(wvL[i].z, zv.z, acc);
                        acc = fmaf(wvL[i].w, zv.w, acc);
                    }
                    #pragma unroll
                    for (int m = 1; m < 64; m <<= 1) acc += __shfl_xor(acc, m, 64);
                    ++R;
                    if (laneL == 0)
                        st_l2(&dhb[growL], scale0 * tanhf(0.01f * (acc + blr)), tagbase + R);
                }

                // ---- gather dh (one word per thread t<256) ----
                {
                    if (t < NH) {
                        u64 w; int it = 0;
                        volatile int* dead = &dead_sh;
                        for (;;) {
                            w = ld_l2(dhb + t);
                            if (tag_ok(w, tagbase + R)) break;
                            if (++it > POLL_CAP) *dead = 1;
                            if (*dead) break;
                        }
                        k_s[NSTATE + t] = __uint_as_float((unsigned)w);
                    }
                    __syncthreads();
                    if (t < NX) yn_s[t] = fmaf(wgt, k_s[t], yn_s[t]);
                }
            } // stages

            __syncthreads();
            if (t < NX) y_s[t] = yn_s[t];
            __syncthreads();
        } // substeps

        if (blk == 0) {
            if (t < NSTATE) out[(iv + 1) * NSTATE + t] = y_s[t];
            if (t < NH)     out[NT * NSTATE + (iv + 1) * NH + t] = y_s[NSTATE + t];
        }
    } // intervals
}

extern "C" void kernel_launch(void* const* d_in, const int* in_sizes, int n_in,
                              void* d_out, int out_size, void* d_ws, size_t ws_size,
                              hipStream_t stream) {
    const float* ts    = (const float*)d_in[0];
    const float* W0    = (const float*)d_in[1];
    const float* b0    = (const float*)d_in[2];
    const float* Wh    = (const float*)d_in[3];
    const float* bh    = (const float*)d_in[4];
    const float* Wl    = (const float*)d_in[5];
    const float* bl    = (const float*)d_in[6];
    const float* betaW = (const float*)d_in[7];
    const float* betab = (const float*)d_in[8];
    const float* hvec  = (const float*)d_in[9];
    const float* scale = (const float*)d_in[10];
    const float* y0log = (const float*)d_in[11];
    float* out = (float*)d_out;

    u64*      zA   = (u64*)d_ws;                          // 8 KB
    u64*      zB   = (u64*)((char*)d_ws + 8192);          // 8 KB
    u64*      dhb  = (u64*)((char*)d_ws + 16384);         // 2 KB
    unsigned* ctrl = (unsigned*)((char*)d_ws + 18432);    // cnt[8], winner word

    // allow 128KB dynamic LDS (h3 weight slice)
    static int lds_set = 0;
    if (!lds_set) {
        hipFuncSetAttribute((const void*)ode_kernel,
                            hipFuncAttributeMaxDynamicSharedMemorySize, 131072);
        lds_set = 1;
    }

    // zero tags + election state (tag 0 != any tagbase+R with nonzero nonce)
    hipMemsetAsync(d_ws, 0, 18432 + 64, stream);
    hipLaunchKernelGGL(ode_kernel, dim3(NLAUNCH), dim3(BS), 131072, stream,
                       ts, W0, b0, Wh, bh, Wl, bl, betaW, betab, hvec, scale,
                       y0log, out, zA, zB, dhb, ctrl);
}

// Round 6
// 22302.782 us; speedup vs baseline: 14.6641x; 1.1303x over previous
//
#include <hip/hip_runtime.h>
#include <math.h>

#define NBLK    32          // worker blocks, all on ONE XCD (its 32 CUs)
#define NLAUNCH 256         // launched blocks; non-elected exit immediately
#define BS      512
#define NSTATE  17
#define NH      256
#define NX      273         // NH + NSTATE
#define WID     1024
#define NT      64
#define NSUB    8
#define ROWS_H  (WID/NBLK)  // 32 rows/block for 1024-wide layers
#define ROWS_L  (NH/NBLK)   // 8 rows/block for the 256-wide output layer
#define POLL_CAP 2000000    // fail fast instead of hanging

typedef unsigned int u32;

__device__ __forceinline__ float softplus_f(float v) {
    return fmaxf(v, 0.f) + log1pf(expf(-fabsf(v)));
}

// ---- flag-gated same-XCD L2 exchange --------------------------------------
// R5 lesson: polling 1024 VALUES via atomic RMW costs ~0.9us/sweep of L2
// atomic throughput (WRITE_SIZE 3.3GB). Only ONE bit needs synchronization.
// New scheme:
//   producer: plain 4B stores (write-through L1 -> XCD L2), per-wave
//             s_waitcnt vmcnt(0) (= store-ack at L2, LLVM's release idiom),
//             block barrier, ONE no-return global_atomic_add (no sc bits ->
//             serviced at local XCD L2) to flag[R&7].
//   consumer: t0 spins on flag via atomic add-0 sc0 (L1-bypassing, proven
//             R5), barrier, then buffer_inv (L1-ONLY invalidate; L1 is
//             write-through so no dirty data can be lost -> kills the R4
//             stale-L1 trap), then plain CACHED loads (miss L1, hit L2).
// Flags rotate mod 8 with monotone targets (round skew provably <=1, so
// 8-deep is ample); memset zeroes them each launch; 4B stores cannot tear.
#define FLG_STRIDE 16   // u32s -> 64B, one flag per cacheline

__device__ __forceinline__ void flag_add(u32* flags, unsigned R) {
    u32* fp = flags + (R & 7) * FLG_STRIDE;
    asm volatile("global_atomic_add %0, %1, off" :: "v"(fp), "v"(1u) : "memory");
}
__device__ __forceinline__ u32 flag_read(u32* flags, unsigned R) {
    u32* fp = flags + (R & 7) * FLG_STRIDE;
    u32 cur;
    asm volatile("global_atomic_add %0, %1, %2, off sc0\n\t"
                 "s_waitcnt vmcnt(0)"
                 : "=&v"(cur) : "v"(fp), "v"(0u) : "memory");
    return cur;
}
// all threads call; rows already stored by their owning lanes
__device__ __forceinline__ void publish(u32* flags, unsigned R, int t) {
    asm volatile("s_waitcnt vmcnt(0)" ::: "memory");   // per-wave store-ack at L2
    __syncthreads();                                   // all waves acked
    if (t == 0) flag_add(flags, R);                    // fire-and-forget
}
__device__ __forceinline__ void wait_flag(u32* flags, unsigned R, int t) {
    if (t == 0) {
        const unsigned tgt = (unsigned)NBLK * (((R - 1) >> 3) + 1);
        int it = 0;
        while (flag_read(flags, R) < tgt && ++it < POLL_CAP) {}
    }
    __syncthreads();
    // L1-only invalidate: next loads miss L1 and fetch fresh data from the
    // shared XCD L2 (the coherence point all producers wrote through to).
    asm volatile("buffer_inv" ::: "memory");
}
// wait + gather the 1024-float buffer into LDS (thread t owns floats 2t,2t+1)
__device__ __forceinline__ void consume_z(const float* __restrict__ buf,
                                          u32* flags, unsigned R,
                                          float* __restrict__ z_s, int t) {
    wait_flag(flags, R, t);
    float2 v = *(const float2*)(buf + 2 * t);
    *(float2*)(z_s + 2 * t) = v;
    __syncthreads();
}

extern "C" __global__ __launch_bounds__(BS, 2) void ode_kernel(
    const float* __restrict__ ts,   const float* __restrict__ W0,
    const float* __restrict__ b0,   const float* __restrict__ Wh,
    const float* __restrict__ bh,   const float* __restrict__ Wl,
    const float* __restrict__ bl,   const float* __restrict__ betaW,
    const float* __restrict__ betab,const float* __restrict__ hvec,
    const float* __restrict__ scale,const float* __restrict__ y0log,
    float* __restrict__ out, float* zA, float* zB, float* dhb,
    u32* flags, unsigned* ctrl)
{
    const int t = threadIdx.x;

    __shared__ int   role_sh;
    __shared__ float y_s[NX];
    __shared__ float yn_s[NX];
    __shared__ float xm[NX];     // MLP-ordered input: [h(256), state(17)]
    __shared__ float k_s[NX];
    __shared__ float z_s[WID];
    __shared__ float red[8];
    __shared__ float dt_sh;
    extern __shared__ float wh2[];   // dynamic: 32 rows x 1024 of layer-3 (128 KB)

    // ---- XCD election (MALL atomics, one-time): first XCD with NBLK blocks
    // wins. 256 blocks, ~137KB LDS -> 1 block/CU, all co-resident.
    if (t == 0) {
        int xcd;
        asm volatile("s_getreg_b32 %0, hwreg(HW_REG_XCC_ID)" : "=s"(xcd));
        xcd &= 7;
        unsigned rk = atomicAdd(&ctrl[xcd], 1u);
        if (rk == NBLK - 1) atomicCAS(&ctrl[8], 0u, (unsigned)(xcd + 1));
        unsigned w; int it = 0;
        do {
            w = __hip_atomic_load(&ctrl[8], __ATOMIC_RELAXED, __HIP_MEMORY_SCOPE_AGENT);
        } while (w == 0u && ++it < POLL_CAP);
        role_sh = (w != 0u && xcd == (int)w - 1 && rk < NBLK) ? (int)rk : -1;
    }
    __syncthreads();
    const int blk = role_sh;
    if (blk < 0) return;

    const float scale0 = scale[0];
    const float betab0 = betab[0];
    unsigned R = 0;   // exchange round; identical sequence on all workers

    const int rowH = t >> 4, laneH = t & 15;
    const int growH = blk * ROWS_H + rowH;
    const int rowL = t >> 6, laneL = t & 63;
    const int growL = blk * ROWS_L + rowL;

    // ---- loop-invariant scalars ----
    const float b0r = b0[growH];
    float bhr[3];
    bhr[0] = bh[growH]; bhr[1] = bh[WID + growH]; bhr[2] = bh[2 * WID + growH];
    const float blr    = bl[growL];
    const float betaWr = (t < NH) ? betaW[t] : 0.f;
    const float* wlp = Wl + (size_t)growL * WID + laneL * 4;

    // ---- weight residency: h1,h2 in VGPRs (128), h3 slice in LDS (128KB),
    //      W0 in 18 regs, Wl streamed per stage (L2-resident).
    float4 wv0[16], wv1[16];
    {
        const float* whp = Wh + (size_t)growH * WID + laneH * 4;
        #pragma unroll
        for (int i = 0; i < 16; i++) wv0[i] = *(const float4*)(whp + i * 64);
        #pragma unroll
        for (int i = 0; i < 16; i++) wv1[i] = *(const float4*)(whp + WID * WID + i * 64);
    }
    {   // copy layer-3 row slice into LDS (coalesced float4)
        const float* src = Wh + 2 * (size_t)WID * WID + (size_t)blk * ROWS_H * WID;
        for (int i = t * 4; i < ROWS_H * WID; i += BS * 4)
            *(float4*)&wh2[i] = *(const float4*)&src[i];
    }
    float w0r[18];
    {
        const float* w0p = W0 + (size_t)growH * NX;
        #pragma unroll
        for (int i = 0; i < 18; i++) {
            int c = laneH + i * 16;
            w0r[i] = (c < NX) ? w0p[c] : 0.f;
        }
    }

    // ---- y0 = [softmax(y0_log), hvec] ----
    if (t < NSTATE) {
        float m = -1e30f;
        for (int j = 0; j < NSTATE; j++) m = fmaxf(m, y0log[j]);
        float ssum = 0.f;
        for (int j = 0; j < NSTATE; j++) ssum += expf(y0log[j] - m);
        y_s[t] = expf(y0log[t] - m) / ssum;
    }
    if (t < NH) y_s[NSTATE + t] = hvec[t];
    __syncthreads();

    if (blk == 0) {
        if (t < NSTATE) out[t] = y_s[t];
        if (t < NH)     out[NT * NSTATE + t] = y_s[NSTATE + t];
    }

    const float c_xi = 13.f / 12.f, c_mu = 0.041f / 12.f, c_sig = 91.f / 12.f,
                c_nu = 36.f / 12.f, c_gam = 1.8f / 12.f;

    for (int iv = 0; iv < NT - 1; iv++) {
        if (t == 0) dt_sh = (ts[iv + 1] - ts[iv]) * (1.f / NSUB);
        __syncthreads();
        const float dt = dt_sh;

        for (int sub = 0; sub < NSUB; sub++) {
            if (t < NX) yn_s[t] = y_s[t];

            for (int s = 0; s < 4; s++) {
                const float a   = (s == 0) ? 0.f : ((s == 3) ? 1.f : 0.5f);
                const float wgt = ((s == 0) || (s == 3)) ? dt * (1.f / 6.f) : dt * (1.f / 3.f);
                const float adt = a * dt;

                // ---- stage input, built directly in MLP order [h, state] ----
                if (t < NX) {
                    const int src = (t < NH) ? (NSTATE + t) : (t - NH);
                    float v = y_s[src];
                    if (s != 0) v = fmaf(adt, k_s[src], v);
                    xm[t] = v;
                }
                __syncthreads();

                // ---- L0: 1024x273, weights in regs (fmaf-pinned) ----
                {
                    float acc = 0.f;
                    #pragma unroll
                    for (int i = 0; i < 18; i++) {
                        int c = laneH + i * 16;
                        if (c < NX) acc = fmaf(w0r[i], xm[c], acc);
                    }
                    #pragma unroll
                    for (int m = 1; m < 16; m <<= 1) acc += __shfl_xor(acc, m, 16);
                    if (laneH == 0) zA[growH] = softplus_f(acc + b0r);
                    ++R;
                    publish(flags, R, t);
                }

                // ---- beta head + dstate: overlaps other blocks' publishes ----
                {
                    if (t < NH) {
                        float p = betaWr * xm[t];
                        #pragma unroll
                        for (int m = 1; m < 64; m <<= 1) p += __shfl_xor(p, m, 64);
                        if ((t & 63) == 0) red[t >> 6] = p;
                    }
                    __syncthreads();
                    if (t == 0) {
                        const float* xs = xm + NH;
                        float sd  = red[0] + red[1] + red[2] + red[3] + betab0;
                        float bb1 = 8.f / (1.f + expf(-sd)) + 25.f;
                        float bb2 = 0.5f * bb1, bb3 = 0.35f * bb1, bb4 = 0.25f * bb1;
                        float M  = xs[0],  S1 = xs[1],  E1 = xs[2],  E2 = xs[3];
                        float E3 = xs[4],  E4 = xs[5],  I1 = xs[6],  I2 = xs[7];
                        float I3 = xs[8],  I4 = xs[9],  R1 = xs[10], R2 = xs[11];
                        float R3 = xs[12], R4 = xs[13], S2 = xs[14], S3 = xs[15];
                        float S4 = xs[16];
                        float I = I1 + I2 + I3 + I4, Rs = R1 + R2 + R3 + R4;
                        k_s[0]  = Rs * c_mu - (c_xi + c_mu) * M;
                        k_s[1]  = c_mu * (1.f - Rs) + c_xi * M - c_mu * S1 - bb1 * I * S1;
                        k_s[2]  = bb1 * I * S1 - (c_mu + c_sig) * E1;
                        k_s[3]  = bb2 * I * S2 - (c_mu + c_sig) * E2;
                        k_s[4]  = bb3 * I * S3 - (c_mu + c_sig) * E3;
                        k_s[5]  = bb4 * I * S4 - (c_mu + c_sig) * E4;
                        k_s[6]  = c_sig * E1 - (c_nu + c_mu) * I1;
                        k_s[7]  = c_sig * E2 - (c_nu + c_mu) * I2;
                        k_s[8]  = c_sig * E3 - (c_nu + c_mu) * I3;
                        k_s[9]  = c_sig * E4 - (c_nu + c_mu) * I4;
                        k_s[10] = c_nu * I1 - (c_mu + c_gam) * R1;
                        k_s[11] = c_nu * I2 - (c_mu + c_gam) * R2;
                        k_s[12] = c_nu * I3 - (c_mu + c_gam) * R3;
                        k_s[13] = c_nu * I4 - (c_mu + c_gam) * R4;
                        k_s[14] = c_gam * R1 - c_mu * S2 - bb2 * I * S2;
                        k_s[15] = c_gam * R2 - c_mu * S3 - bb3 * I * S3;
                        k_s[16] = c_gam * (R3 + R4) - c_mu * S4 - bb4 * I * S4;
                    }
                    // k_s[0..16] next read only after later consume barriers.
                }

                // ---- h1, h2: weights in registers (fmaf-pinned) ----
                auto hidden = [&](const float4 (&wv)[16], const float* zin,
                                  float* zout, float bias) {
                    consume_z(zin, flags, R, z_s, t);
                    float acc = 0.f;
                    #pragma unroll
                    for (int i = 0; i < 16; i++) {
                        float4 zv = *(const float4*)(z_s + (laneH * 4 + i * 64));
                        acc = fmaf(wv[i].x, zv.x, acc);
                        acc = fmaf(wv[i].y, zv.y, acc);
                        acc = fmaf(wv[i].z, zv.z, acc);
                        acc = fmaf(wv[i].w, zv.w, acc);
                    }
                    #pragma unroll
                    for (int m = 1; m < 16; m <<= 1) acc += __shfl_xor(acc, m, 16);
                    if (laneH == 0) zout[growH] = softplus_f(acc + bias);
                    ++R;
                    publish(flags, R, t);
                };

                hidden(wv0, zA, zB, bhr[0]);
                hidden(wv1, zB, zA, bhr[1]);

                // prefetch Wl row slice (L2-resident); overlaps h3 exchange
                float4 wvL[4];
                #pragma unroll
                for (int i = 0; i < 4; i++) wvL[i] = *(const float4*)(wlp + i * 256);

                // ---- h3: weights from LDS (fmaf-pinned) ----
                {
                    consume_z(zA, flags, R, z_s, t);
                    const float* wr = wh2 + rowH * WID + laneH * 4;
                    float acc = 0.f;
                    #pragma unroll
                    for (int i = 0; i < 16; i++) {
                        float4 wv4 = *(const float4*)(wr + i * 64);
                        float4 zv  = *(const float4*)(z_s + (laneH * 4 + i * 64));
                        acc = fmaf(wv4.x, zv.x, acc);
                        acc = fmaf(wv4.y, zv.y, acc);
                        acc = fmaf(wv4.z, zv.z, acc);
                        acc = fmaf(wv4.w, zv.w, acc);
                    }
                    #pragma unroll
                    for (int m = 1; m < 16; m <<= 1) acc += __shfl_xor(acc, m, 16);
                    if (laneH == 0) zB[growH] = softplus_f(acc + bhr[2]);
                    ++R;
                    publish(flags, R, t);
                }

                // ---- Wl: 256x1024, 8 rows/block; tanh epilogue ----
                {
                    consume_z(zB, flags, R, z_s, t);
                    float acc = 0.f;
                    #pragma unroll
                    for (int i = 0; i < 4; i++) {
                        float4 zv = *(const float4*)(z_s + (laneL * 4 + i * 256));
                        acc = fmaf(wvL[i].x, zv.x, acc);
                        acc = fmaf(wvL[i].y, zv.y, acc);
                        acc = fmaf(wvL[i].z, zv.z, acc);
                        acc = fmaf(wvL[i].w, zv.w, acc);
                    }
                    #pragma unroll
                    for (int m = 1; m < 64; m <<= 1) acc += __shfl_xor(acc, m, 64);
                    if (laneL == 0) dhb[growL] = scale0 * tanhf(0.01f * (acc + blr));
                    ++R;
                    publish(flags, R, t);
                }

                // ---- gather dh ----
                {
                    wait_flag(flags, R, t);
                    if (t < NH) k_s[NSTATE + t] = dhb[t];
                    __syncthreads();
                    if (t < NX) yn_s[t] = fmaf(wgt, k_s[t], yn_s[t]);
                }
            } // stages

            __syncthreads();
            if (t < NX) y_s[t] = yn_s[t];
            __syncthreads();
        } // substeps

        if (blk == 0) {
            if (t < NSTATE) out[(iv + 1) * NSTATE + t] = y_s[t];
            if (t < NH)     out[NT * NSTATE + (iv + 1) * NH + t] = y_s[NSTATE + t];
        }
    } // intervals
}

extern "C" void kernel_launch(void* const* d_in, const int* in_sizes, int n_in,
                              void* d_out, int out_size, void* d_ws, size_t ws_size,
                              hipStream_t stream) {
    const float* ts    = (const float*)d_in[0];
    const float* W0    = (const float*)d_in[1];
    const float* b0    = (const float*)d_in[2];
    const float* Wh    = (const float*)d_in[3];
    const float* bh    = (const float*)d_in[4];
    const float* Wl    = (const float*)d_in[5];
    const float* bl    = (const float*)d_in[6];
    const float* betaW = (const float*)d_in[7];
    const float* betab = (const float*)d_in[8];
    const float* hvec  = (const float*)d_in[9];
    const float* scale = (const float*)d_in[10];
    const float* y0log = (const float*)d_in[11];
    float* out = (float*)d_out;

    float*    zA    = (float*)d_ws;                       // 4 KB
    float*    zB    = (float*)((char*)d_ws + 4096);       // 4 KB
    float*    dhb   = (float*)((char*)d_ws + 8192);       // 1 KB
    u32*      flags = (u32*)((char*)d_ws + 9216);         // 8 x 64B
    unsigned* ctrl  = (unsigned*)((char*)d_ws + 9728);    // cnt[8], winner

    // allow 128KB dynamic LDS (h3 weight slice)
    static int lds_set = 0;
    if (!lds_set) {
        hipFuncSetAttribute((const void*)ode_kernel,
                            hipFuncAttributeMaxDynamicSharedMemorySize, 131072);
        lds_set = 1;
    }

    // zero exchange buffers + flags + election state
    hipMemsetAsync(d_ws, 0, 10240, stream);
    hipLaunchKernelGGL(ode_kernel, dim3(NLAUNCH), dim3(BS), 131072, stream,
                       ts, W0, b0, Wh, bh, Wl, bl, betaW, betab, hvec, scale,
                       y0log, out, zA, zB, dhb, flags, ctrl);
}